// Round 1
// baseline (15319.388 us; speedup 1.0000x reference)
//
#include <hip/hip_runtime.h>

#define B_ 128
#define T_ 256
#define IN_ 128
#define G_ 5
#define H_ 512
#define G3_ 1536
#define E_ 1024
#define L_ 256
#define LG_ 251
#define INPG_ 133

#define MU_OFF (B_*T_*IN_)            /* 4194304 */
#define LV_OFF (MU_OFF + B_*LG_)      /* 4226432 */

__device__ __forceinline__ float bf2f(unsigned short s) {
    return __uint_as_float(((unsigned)s) << 16);
}
__device__ __forceinline__ unsigned short f2bf(float f) {
    unsigned x = __float_as_uint(f);
    unsigned r = (x + 0x7fffu + ((x >> 16) & 1u)) >> 16;
    return (unsigned short)r;
}

// ---- prep: W[N][K] fp32 -> tiled bf16 out[KC][N][4] (ushort4 per (kc,n))
__global__ void tile_w(const float* __restrict__ W, ushort4* __restrict__ out,
                       int N, int K, int KC) {
    int id = blockIdx.x * 256 + threadIdx.x;
    if (id >= KC * N) return;
    int kc = id / N, n = id - kc * N;
    int k = kc * 4;
    ushort4 u;
    u.x = f2bf(k + 0 < K ? W[n * K + k + 0] : 0.f);
    u.y = f2bf(k + 1 < K ? W[n * K + k + 1] : 0.f);
    u.z = f2bf(k + 2 < K ? W[n * K + k + 2] : 0.f);
    u.w = f2bf(k + 3 < K ? W[n * K + k + 3] : 0.f);
    out[kc * N + n] = u;
}

__global__ void zero_hf(float* a, float* b, int n) {
    int id = blockIdx.x * 256 + threadIdx.x;
    if (id < n) { a[id] = 0.f; b[id] = 0.f; }
}

// out[:,0,:] = x[:,0,:IN]
__global__ void note0_k(const float* __restrict__ x, float* __restrict__ out) {
    int id = blockIdx.x * 256 + threadIdx.x;
    if (id >= B_ * IN_) return;
    int b = id >> 7, n = id & 127;
    out[(b * T_) * IN_ + n] = x[(b * T_) * INPG_ + n];
}

__global__ void concat_h(const float* __restrict__ hf, const float* __restrict__ hb,
                         float* __restrict__ hidden) {
    int id = blockIdx.x * 256 + threadIdx.x;
    if (id >= B_ * E_) return;
    int b = id >> 10, c = id & 1023;
    hidden[id] = (c < H_) ? hf[b * H_ + c] : hb[b * H_ + (c - H_)];
}

// One GRU step. Block = 16 batch x 32 h-cols. Grid = bpd per direction (dir1 optional).
__global__ __launch_bounds__(256) void gru_step(
    const float* __restrict__ x0, int xb0, int xo0,
    const float* __restrict__ hin0, float* __restrict__ hout0,
    const ushort4* __restrict__ Wx0, const ushort4* __restrict__ Wh0,
    const float* __restrict__ bi0, const float* __restrict__ bh0,
    const float* __restrict__ x1, int xb1, int xo1,
    const float* __restrict__ hin1, float* __restrict__ hout1,
    const ushort4* __restrict__ Wx1, const ushort4* __restrict__ Wh1,
    const float* __restrict__ bi1, const float* __restrict__ bh1,
    int KCx, int Kx, int bpd)
{
    int bid = blockIdx.x;
    int dir = (bid >= bpd) ? 1 : 0;
    const float* xp; int xb, xo; const float* hin; float* hout;
    const ushort4 *Wx, *Wh; const float *bi, *bh;
    if (dir) { bid -= bpd; xp=x1; xb=xb1; xo=xo1; hin=hin1; hout=hout1; Wx=Wx1; Wh=Wh1; bi=bi1; bh=bh1; }
    else     {             xp=x0; xb=xb0; xo=xo0; hin=hin0; hout=hout0; Wx=Wx0; Wh=Wh0; bi=bi0; bh=bh0; }

    int bt = bid >> 4, cs = bid & 15;
    int b0 = bt << 4;
    __shared__ float hs[16][512];
    __shared__ float xs[16][136];
    int tid = threadIdx.x;
    // stage h tile (16 x 512), coalesced float4
    #pragma unroll
    for (int i = 0; i < 8; ++i) {
        int idx = tid + (i << 8);
        int r = idx >> 7, c = (idx & 127) << 2;
        *(float4*)&hs[r][c] = *(const float4*)&hin[(b0 + r) * H_ + c];
    }
    // stage x tile (16 x Kx, zero-padded to KCx*4)
    int KX4 = KCx << 2;
    for (int r = 0; r < 16; ++r) {
        for (int c = tid; c < KX4; c += 256)
            xs[r][c] = (c < Kx) ? xp[(b0 + r) * xb + xo + c] : 0.f;
    }
    __syncthreads();

    int col = tid & 31, p = tid >> 5;
    int j = (cs << 5) + col;
    int jr = j, jz = H_ + j, jn = 2 * H_ + j;
    int ba = p << 1, bb = ba + 1;
    float ar0=0,ar1=0,az0=0,az1=0,ain0=0,ain1=0,ahn0=0,ahn1=0;

    // x-part: accumulates into r,z (combined) and inn (separate)
    for (int kc = 0; kc < KCx; ++kc) {
        ushort4 ur = Wx[kc * G3_ + jr];
        ushort4 uz = Wx[kc * G3_ + jz];
        ushort4 un = Wx[kc * G3_ + jn];
        float4 xa = *(const float4*)&xs[ba][kc << 2];
        float4 xv = *(const float4*)&xs[bb][kc << 2];
        float wr0=bf2f(ur.x),wr1=bf2f(ur.y),wr2=bf2f(ur.z),wr3=bf2f(ur.w);
        float wz0=bf2f(uz.x),wz1=bf2f(uz.y),wz2=bf2f(uz.z),wz3=bf2f(uz.w);
        float wn0=bf2f(un.x),wn1=bf2f(un.y),wn2=bf2f(un.z),wn3=bf2f(un.w);
        ar0 += xa.x*wr0 + xa.y*wr1 + xa.z*wr2 + xa.w*wr3;
        ar1 += xv.x*wr0 + xv.y*wr1 + xv.z*wr2 + xv.w*wr3;
        az0 += xa.x*wz0 + xa.y*wz1 + xa.z*wz2 + xa.w*wz3;
        az1 += xv.x*wz0 + xv.y*wz1 + xv.z*wz2 + xv.w*wz3;
        ain0 += xa.x*wn0 + xa.y*wn1 + xa.z*wn2 + xa.w*wn3;
        ain1 += xv.x*wn0 + xv.y*wn1 + xv.z*wn2 + xv.w*wn3;
    }
    // h-part: r,z into same accs; hn separate (multiplied by r inside tanh)
    #pragma unroll 4
    for (int kc = 0; kc < 128; ++kc) {
        ushort4 ur = Wh[kc * G3_ + jr];
        ushort4 uz = Wh[kc * G3_ + jz];
        ushort4 un = Wh[kc * G3_ + jn];
        float4 ha = *(const float4*)&hs[ba][kc << 2];
        float4 hv = *(const float4*)&hs[bb][kc << 2];
        float wr0=bf2f(ur.x),wr1=bf2f(ur.y),wr2=bf2f(ur.z),wr3=bf2f(ur.w);
        float wz0=bf2f(uz.x),wz1=bf2f(uz.y),wz2=bf2f(uz.z),wz3=bf2f(uz.w);
        float wn0=bf2f(un.x),wn1=bf2f(un.y),wn2=bf2f(un.z),wn3=bf2f(un.w);
        ar0 += ha.x*wr0 + ha.y*wr1 + ha.z*wr2 + ha.w*wr3;
        ar1 += hv.x*wr0 + hv.y*wr1 + hv.z*wr2 + hv.w*wr3;
        az0 += ha.x*wz0 + ha.y*wz1 + ha.z*wz2 + ha.w*wz3;
        az1 += hv.x*wz0 + hv.y*wz1 + hv.z*wz2 + hv.w*wz3;
        ahn0 += ha.x*wn0 + ha.y*wn1 + ha.z*wn2 + ha.w*wn3;
        ahn1 += hv.x*wn0 + hv.y*wn1 + hv.z*wn2 + hv.w*wn3;
    }
    float hpa = hs[ba][j], hpb = hs[bb][j];
    float bir = bi[jr], bhr = bh[jr];
    float biz = bi[jz], bhz = bh[jz];
    float bin = bi[jn], bhn = bh[jn];
    float r_a = 1.f / (1.f + __expf(-(ar0 + bir + bhr)));
    float z_a = 1.f / (1.f + __expf(-(az0 + biz + bhz)));
    float n_a = tanhf(ain0 + bin + r_a * (ahn0 + bhn));
    hout[(b0 + ba) * H_ + j] = (1.f - z_a) * n_a + z_a * hpa;
    float r_b = 1.f / (1.f + __expf(-(ar1 + bir + bhr)));
    float z_b = 1.f / (1.f + __expf(-(az1 + biz + bhz)));
    float n_b = tanhf(ain1 + bin + r_b * (ahn1 + bhn));
    hout[(b0 + bb) * H_ + j] = (1.f - z_b) * n_b + z_b * hpb;
}

// note_t = h_t @ W_dec1.T + b_dec1 -> out[:, t, :]
__global__ __launch_bounds__(256) void note_proj(
    const float* __restrict__ h, const ushort4* __restrict__ Wd,
    const float* __restrict__ bd, float* __restrict__ out, int t)
{
    int bt = blockIdx.x >> 3, ncs = blockIdx.x & 7;
    int b0 = bt << 4;
    __shared__ float hs[16][512];
    int tid = threadIdx.x;
    #pragma unroll
    for (int i = 0; i < 8; ++i) {
        int idx = tid + (i << 8);
        int r = idx >> 7, c = (idx & 127) << 2;
        *(float4*)&hs[r][c] = *(const float4*)&h[(b0 + r) * H_ + c];
    }
    __syncthreads();
    int n = (ncs << 4) + (tid & 15), b = tid >> 4;
    float acc = 0.f;
    #pragma unroll 4
    for (int kc = 0; kc < 128; ++kc) {
        ushort4 u = Wd[kc * IN_ + n];
        float4 h4 = *(const float4*)&hs[b][kc << 2];
        acc += h4.x*bf2f(u.x) + h4.y*bf2f(u.y) + h4.z*bf2f(u.z) + h4.w*bf2f(u.w);
    }
    out[((b0 + b) * T_ + t) * IN_ + n] = acc + bd[n];
}

// C[m][n] = act( sum_k A[m][k] * W[n][k] + bias[n] ), W tiled bf16 [KC][N][4]
// grid: x = ceil(N/64), y = M/32; block 256
__global__ __launch_bounds__(256) void gemm_t4(
    const float* __restrict__ A, const ushort4* __restrict__ Wt,
    const float* __restrict__ bias, float* __restrict__ C,
    int M, int N, int K, int act)
{
    int nb = blockIdx.x, mb = blockIdx.y;
    int tid = threadIdx.x;
    int n = nb * 64 + (tid & 63);
    int mq = tid >> 6;
    int m0 = mb * 32;
    __shared__ float As[32][36];
    float acc[8];
    #pragma unroll
    for (int i = 0; i < 8; ++i) acc[i] = 0.f;
    for (int k0 = 0; k0 < K; k0 += 32) {
        int r = tid >> 3, c = (tid & 7) << 2;
        float4 v = *(const float4*)&A[(m0 + r) * K + k0 + c];
        As[r][c] = v.x; As[r][c+1] = v.y; As[r][c+2] = v.z; As[r][c+3] = v.w;
        __syncthreads();
        #pragma unroll
        for (int kc = 0; kc < 8; ++kc) {
            float w0=0.f, w1=0.f, w2=0.f, w3=0.f;
            if (n < N) {
                ushort4 u = Wt[((k0 >> 2) + kc) * N + n];
                w0 = bf2f(u.x); w1 = bf2f(u.y); w2 = bf2f(u.z); w3 = bf2f(u.w);
            }
            #pragma unroll
            for (int i = 0; i < 8; ++i) {
                int m = mq * 8 + i;
                acc[i] += As[m][kc*4+0]*w0 + As[m][kc*4+1]*w1
                        + As[m][kc*4+2]*w2 + As[m][kc*4+3]*w3;
            }
        }
        __syncthreads();
    }
    if (n < N) {
        #pragma unroll
        for (int i = 0; i < 8; ++i) {
            int m = m0 + mq * 8 + i;
            float v = acc[i] + bias[n];
            if (act == 1) v = (v >= 0.f) ? v : 0.01f * v;
            C[m * N + n] = v;
        }
    }
}

// z / concat genre: zc[b][c<251] = mu + exp(0.5 lv)*eps ; zc[b][251..255] = genre
__global__ void z_k(const float* __restrict__ out, const float* __restrict__ eps,
                    const float* __restrict__ genre, float* __restrict__ zc) {
    int id = blockIdx.x * 256 + threadIdx.x;
    if (id >= B_ * L_) return;
    int b = id >> 8, c = id & 255;
    float v;
    if (c < LG_) {
        float mu = out[MU_OFF + b * LG_ + c];
        float lv = out[LV_OFF + b * LG_ + c];
        v = mu + expf(0.5f * lv) * eps[b * LG_ + c];
    } else {
        v = genre[b * G_ + (c - LG_)];
    }
    zc[id] = v;
}

extern "C" void kernel_launch(void* const* d_in, const int* in_sizes, int n_in,
                              void* d_out, int out_size, void* d_ws, size_t ws_size,
                              hipStream_t stream) {
    (void)in_sizes; (void)n_in; (void)out_size; (void)ws_size;
    const float* x      = (const float*)d_in[0];
    const float* genre  = (const float*)d_in[1];
    const float* eps    = (const float*)d_in[2];
    const float* Wih_e  = (const float*)d_in[3];
    const float* Whh_e  = (const float*)d_in[4];
    const float* bih_e  = (const float*)d_in[5];
    const float* bhh_e  = (const float*)d_in[6];
    const float* Wih_be = (const float*)d_in[7];
    const float* Whh_be = (const float*)d_in[8];
    const float* bih_be = (const float*)d_in[9];
    const float* bhh_be = (const float*)d_in[10];
    const float* Wih_d  = (const float*)d_in[11];
    const float* Whh_d  = (const float*)d_in[12];
    const float* bih_d  = (const float*)d_in[13];
    const float* bhh_d  = (const float*)d_in[14];
    const float* W_mu0  = (const float*)d_in[15];
    const float* b_mu0  = (const float*)d_in[16];
    const float* W_mu1  = (const float*)d_in[17];
    const float* b_mu1  = (const float*)d_in[18];
    const float* W_lv0  = (const float*)d_in[19];
    const float* b_lv0  = (const float*)d_in[20];
    const float* W_lv1  = (const float*)d_in[21];
    const float* b_lv1  = (const float*)d_in[22];
    const float* W_lat0 = (const float*)d_in[23];
    const float* b_lat0 = (const float*)d_in[24];
    const float* W_lat1 = (const float*)d_in[25];
    const float* b_lat1 = (const float*)d_in[26];
    const float* W_dec1 = (const float*)d_in[27];
    const float* b_dec1 = (const float*)d_in[28];
    float* out = (float*)d_out;

    char* ws = (char*)d_ws;
    size_t off = 0;
    auto alloc = [&](size_t bytes) -> char* {
        char* p = ws + off;
        off = (off + bytes + 255) & ~(size_t)255;
        return p;
    };
    float* h_fwd_a = (float*)alloc(B_*H_*4);
    float* h_fwd_b = (float*)alloc(B_*H_*4);
    float* h_bwd_a = (float*)alloc(B_*H_*4);
    float* h_bwd_b = (float*)alloc(B_*H_*4);
    float* h_dec_a = (float*)alloc(B_*H_*4);
    float* h_dec_b = (float*)alloc(B_*H_*4);
    float* hidden  = (float*)alloc(B_*E_*4);
    float* t0buf   = (float*)alloc(B_*E_*4);
    float* t1buf   = (float*)alloc(B_*E_*4);
    float* zcbuf   = (float*)alloc(B_*L_*4);
    float* t2buf   = (float*)alloc(B_*L_*4);

    ushort4* T_Wih_e  = (ushort4*)alloc((size_t)34 * G3_ * 8);
    ushort4* T_Whh_e  = (ushort4*)alloc((size_t)128 * G3_ * 8);
    ushort4* T_Wih_be = (ushort4*)alloc((size_t)34 * G3_ * 8);
    ushort4* T_Whh_be = (ushort4*)alloc((size_t)128 * G3_ * 8);
    ushort4* T_Wih_d  = (ushort4*)alloc((size_t)32 * G3_ * 8);
    ushort4* T_Whh_d  = (ushort4*)alloc((size_t)128 * G3_ * 8);
    ushort4* T_Wdec1  = (ushort4*)alloc((size_t)128 * IN_ * 8);
    ushort4* T_Wmu0   = (ushort4*)alloc((size_t)256 * E_ * 8);
    ushort4* T_Wmu1   = (ushort4*)alloc((size_t)256 * LG_ * 8);
    ushort4* T_Wlv0   = (ushort4*)alloc((size_t)256 * E_ * 8);
    ushort4* T_Wlv1   = (ushort4*)alloc((size_t)256 * LG_ * 8);
    ushort4* T_Wlat0  = (ushort4*)alloc((size_t)64 * L_ * 8);
    ushort4* T_Wlat1  = (ushort4*)alloc((size_t)64 * H_ * 8);

    auto tile = [&](const float* W, ushort4* dst, int N, int K) {
        int KC = (K + 3) / 4;
        int tot = KC * N;
        tile_w<<<(tot + 255) / 256, 256, 0, stream>>>(W, dst, N, K, KC);
    };
    tile(Wih_e,  T_Wih_e,  G3_, INPG_);
    tile(Whh_e,  T_Whh_e,  G3_, H_);
    tile(Wih_be, T_Wih_be, G3_, INPG_);
    tile(Whh_be, T_Whh_be, G3_, H_);
    tile(Wih_d,  T_Wih_d,  G3_, IN_);
    tile(Whh_d,  T_Whh_d,  G3_, H_);
    tile(W_dec1, T_Wdec1,  IN_, H_);
    tile(W_mu0,  T_Wmu0,   E_,  E_);
    tile(W_mu1,  T_Wmu1,   LG_, E_);
    tile(W_lv0,  T_Wlv0,   E_,  E_);
    tile(W_lv1,  T_Wlv1,   LG_, E_);
    tile(W_lat0, T_Wlat0,  L_,  L_);
    tile(W_lat1, T_Wlat1,  H_,  L_);

    zero_hf<<<(B_*H_ + 255) / 256, 256, 0, stream>>>(h_fwd_a, h_bwd_a, B_*H_);
    note0_k<<<(B_*IN_ + 255) / 256, 256, 0, stream>>>(x, out);

    // -------- encoders (fwd + bwd in one launch per step) --------
    for (int t = 0; t < T_; ++t) {
        const float* hinf = (t & 1) ? h_fwd_b : h_fwd_a;
        float*       houtf = (t & 1) ? h_fwd_a : h_fwd_b;
        const float* hinb = (t & 1) ? h_bwd_b : h_bwd_a;
        float*       houtb = (t & 1) ? h_bwd_a : h_bwd_b;
        gru_step<<<256, 256, 0, stream>>>(
            x, T_*INPG_, t*INPG_,         hinf, houtf, T_Wih_e,  T_Whh_e,  bih_e,  bhh_e,
            x, T_*INPG_, (T_-1-t)*INPG_,  hinb, houtb, T_Wih_be, T_Whh_be, bih_be, bhh_be,
            34, INPG_, 128);
    }
    // final hidden states are in *_a (t=255 is odd -> wrote a)

    // -------- MLP bottleneck --------
    concat_h<<<(B_*E_ + 255) / 256, 256, 0, stream>>>(h_fwd_a, h_bwd_a, hidden);
    {
        dim3 g1(16, 4), g2(4, 4), g3(4, 4), g4(8, 4);
        gemm_t4<<<g1, 256, 0, stream>>>(hidden, T_Wmu0, b_mu0, t0buf, B_, E_, E_, 1);
        gemm_t4<<<g2, 256, 0, stream>>>(t0buf, T_Wmu1, b_mu1, out + MU_OFF, B_, LG_, E_, 0);
        gemm_t4<<<g1, 256, 0, stream>>>(hidden, T_Wlv0, b_lv0, t1buf, B_, E_, E_, 1);
        gemm_t4<<<g2, 256, 0, stream>>>(t1buf, T_Wlv1, b_lv1, out + LV_OFF, B_, LG_, E_, 0);
        z_k<<<(B_*L_ + 255) / 256, 256, 0, stream>>>(out, eps, genre, zcbuf);
        gemm_t4<<<g3, 256, 0, stream>>>(zcbuf, T_Wlat0, b_lat0, t2buf, B_, L_, L_, 1);
        gemm_t4<<<g4, 256, 0, stream>>>(t2buf, T_Wlat1, b_lat1, h_dec_a, B_, H_, L_, 0);
    }

    // -------- decoder: h = GRU(note_{t-1}, h); note_t = h @ W_dec1.T + b --------
    for (int t = 1; t < T_; ++t) {
        const float* hin = ((t-1) & 1) ? h_dec_b : h_dec_a;
        float*       hout = ((t-1) & 1) ? h_dec_a : h_dec_b;
        gru_step<<<128, 256, 0, stream>>>(
            out, T_*IN_, (t-1)*IN_, hin, hout, T_Wih_d, T_Whh_d, bih_d, bhh_d,
            out, T_*IN_, (t-1)*IN_, hin, hout, T_Wih_d, T_Whh_d, bih_d, bhh_d,
            32, IN_, 128);
        note_proj<<<64, 256, 0, stream>>>(hout, T_Wdec1, b_dec1, out, t);
    }
}

// Round 2
// 4370.029 us; speedup vs baseline: 3.5056x; 3.5056x over previous
//
#include <hip/hip_runtime.h>

#define B_ 128
#define T_ 256
#define IN_ 128
#define G_ 5
#define H_ 512
#define G3_ 1536
#define E_ 1024
#define L_ 256
#define LG_ 251
#define INPG_ 133

#define MU_OFF (B_*T_*IN_)            /* 4194304 */
#define LV_OFF (MU_OFF + B_*LG_)      /* 4226432 */

typedef __attribute__((ext_vector_type(8))) short bf16x8;
typedef __attribute__((ext_vector_type(4))) float f32x4;

__device__ __forceinline__ float bf2f(unsigned short s) {
    return __uint_as_float(((unsigned)s) << 16);
}
__device__ __forceinline__ unsigned short f2bf(float f) {
    unsigned x = __float_as_uint(f);
    unsigned r = (x + 0x7fffu + ((x >> 16) & 1u)) >> 16;
    return (unsigned short)r;
}
__device__ __forceinline__ float sigf(float v) {
    return 1.f / (1.f + __expf(-v));
}

// =============== prep kernels ===============

// x fp32 [B][T][133] -> xb16 [T][B][160] bf16 (cols 133..159 zero)
__global__ void xpad_k(const float* __restrict__ x, ushort* __restrict__ xb) {
    int id = blockIdx.x * 256 + threadIdx.x;
    if (id >= T_ * B_ * 160) return;
    int t = id / (B_ * 160);
    int rem = id - t * (B_ * 160);
    int b = rem / 160, c = rem - b * 160;
    float v = (c < INPG_) ? x[((size_t)b * T_ + t) * INPG_ + c] : 0.f;
    xb[id] = f2bf(v);
}

// encoder weight pack: WE chunks [(dir*32+cb)*63 + ks][64 lanes][8 bf16]
// planes: ks 0..20 r(cat672), 21..41 z(cat672), 42..46 nx(K160), 47..62 nh(K512)
__global__ void pack_we(const float* __restrict__ Wih_f, const float* __restrict__ Whh_f,
                        const float* __restrict__ Wih_b, const float* __restrict__ Whh_b,
                        ushort* __restrict__ WE) {
    int id = blockIdx.x * 256 + threadIdx.x;   // 258048 total
    int lane = id & 63;
    int rest = id >> 6;
    int ks = rest % 63;
    int cb = (rest / 63) & 31;
    int dir = rest / (63 * 32);
    if (dir >= 2) return;
    const float* Wih = dir ? Wih_b : Wih_f;
    const float* Whh = dir ? Whh_b : Whh_f;
    int n = lane & 15, kb = lane >> 4;
    int p, ksp;
    if (ks < 21)      { p = 0; ksp = ks; }
    else if (ks < 42) { p = 1; ksp = ks - 21; }
    else if (ks < 47) { p = 2; ksp = ks - 42; }
    else              { p = 3; ksp = ks - 47; }
    int j = cb * 16 + n;
    int row = (p == 0) ? j : (p == 1) ? 512 + j : 1024 + j;
    #pragma unroll
    for (int e = 0; e < 8; ++e) {
        int k = ksp * 32 + kb * 8 + e;
        float v;
        if (p == 3)      v = Whh[(size_t)row * 512 + k];
        else if (p == 2) v = (k < INPG_) ? Wih[(size_t)row * INPG_ + k] : 0.f;
        else v = (k < INPG_) ? Wih[(size_t)row * INPG_ + k]
               : (k < 160)   ? 0.f
               : Whh[(size_t)row * 512 + (k - 160)];
        WE[(size_t)id * 8 + e] = f2bf(v);
    }
}

// Wfused[r][c] = sum_m Wih_d[r][m] * Wdec1[m][c]   (1536 x 512, fp32)
__global__ void wfused_k(const float* __restrict__ Wih_d, const float* __restrict__ Wdec1,
                         float* __restrict__ Wf) {
    int id = blockIdx.x * 256 + threadIdx.x;
    if (id >= G3_ * H_) return;
    int r = id >> 9, c = id & 511;
    float s = 0.f;
    for (int m = 0; m < 128; ++m)
        s += Wih_d[(size_t)r * 128 + m] * Wdec1[(size_t)m * 512 + c];
    Wf[id] = s;
}

// bfi[r] = bih_d[r] + sum_m Wih_d[r][m] * b_dec1[m]
__global__ void bfi_k(const float* __restrict__ Wih_d, const float* __restrict__ b_dec1,
                      const float* __restrict__ bih_d, float* __restrict__ bfi) {
    int r = blockIdx.x * 256 + threadIdx.x;
    if (r >= G3_) return;
    float s = bih_d[r];
    for (int m = 0; m < 128; ++m)
        s += Wih_d[(size_t)r * 128 + m] * b_dec1[m];
    bfi[r] = s;
}

// decoder weight pack: WD chunks [cb*64 + p*16 + ks][64][8], K=512 each plane.
// fused=1: p0 = Wf_r+Whh_r, p1 = Wf_z+Whh_z, p2 = Wf_n, p3 = Whh_n
// fused=0: p0 = Whh_r, p1 = Whh_z, p2 = 0, p3 = Whh_n
__global__ void pack_wd(const float* __restrict__ Wf, const float* __restrict__ Whh,
                        ushort* __restrict__ WD, int fused) {
    int id = blockIdx.x * 256 + threadIdx.x;   // 131072 total
    int lane = id & 63;
    int rest = id >> 6;
    int ks = rest & 63;
    int cb = rest >> 6;
    if (cb >= 32) return;
    int p = ks >> 4, ksp = ks & 15;
    int n = lane & 15, kb = lane >> 4;
    int j = cb * 16 + n;
    int row = (p == 0) ? j : (p == 1) ? 512 + j : 1024 + j;
    #pragma unroll
    for (int e = 0; e < 8; ++e) {
        int k = ksp * 32 + kb * 8 + e;
        float v;
        if (p <= 1) v = fused ? (Wf[(size_t)row * 512 + k] + Whh[(size_t)row * 512 + k])
                              : Whh[(size_t)row * 512 + k];
        else if (p == 2) v = fused ? Wf[(size_t)row * 512 + k] : 0.f;
        else v = Whh[(size_t)row * 512 + k];
        WD[(size_t)id * 8 + e] = f2bf(v);
    }
}

__global__ void zero_init(ushort* __restrict__ hb, float* __restrict__ hf) {
    int id = blockIdx.x * 256 + threadIdx.x;
    if (id < 4 * 65536) hb[id] = 0;      // 2 pp x 2 dir x 128 x 512
    if (id < 2 * 65536) hf[id] = 0.f;    // 2 dir x 128 x 512
}

// note0 -> out[:,0,:] and note0f buffer
__global__ void note0_k2(const float* __restrict__ x, float* __restrict__ out,
                         float* __restrict__ note0f) {
    int id = blockIdx.x * 256 + threadIdx.x;
    if (id >= B_ * IN_) return;
    int b = id >> 7, n = id & 127;
    float v = x[((size_t)b * T_) * INPG_ + n];
    out[((size_t)b * T_) * IN_ + n] = v;
    note0f[(size_t)b * 128 + n] = v;
}

__global__ void cvt_h0(const float* __restrict__ src, ushort* __restrict__ dst) {
    int id = blockIdx.x * 256 + threadIdx.x;
    if (id < B_ * H_) dst[id] = f2bf(src[id]);
}

__global__ void concat_h(const float* __restrict__ hf32, float* __restrict__ hidden) {
    // hf32: [2][128][512] -> hidden [128][1024]
    int id = blockIdx.x * 256 + threadIdx.x;
    if (id >= B_ * E_) return;
    int b = id >> 10, c = id & 1023;
    hidden[id] = (c < H_) ? hf32[(size_t)b * 512 + c]
                          : hf32[65536 + (size_t)b * 512 + (c - 512)];
}

// ---- W[N][K] fp32 -> tiled bf16 out[KC][N][4] (ushort4 per (kc,n)) ----
__global__ void tile_w(const float* __restrict__ W, ushort4* __restrict__ out,
                       int N, int K, int KC) {
    int id = blockIdx.x * 256 + threadIdx.x;
    if (id >= KC * N) return;
    int kc = id / N, n = id - kc * N;
    int k = kc * 4;
    ushort4 u;
    u.x = f2bf(k + 0 < K ? W[(size_t)n * K + k + 0] : 0.f);
    u.y = f2bf(k + 1 < K ? W[(size_t)n * K + k + 1] : 0.f);
    u.z = f2bf(k + 2 < K ? W[(size_t)n * K + k + 2] : 0.f);
    u.w = f2bf(k + 3 < K ? W[(size_t)n * K + k + 3] : 0.f);
    out[(size_t)kc * N + n] = u;
}

// =============== recurrent step kernels (MFMA) ===============

// Encoder step: grid 256 = dir(2) x bt(4) x cb(32); block 256 = 4 waves (gate planes).
// A-tile (LDS): 32 batch rows x 672 cols bf16 (stride 680): [x_t pad160 | h 512]
__global__ __launch_bounds__(256) void enc_step(
    const ushort* __restrict__ xb16, const ushort* __restrict__ WE,
    const ushort* __restrict__ hb_in, ushort* __restrict__ hb_out,
    float* __restrict__ hf32,
    const float* __restrict__ bih_f, const float* __restrict__ bhh_f,
    const float* __restrict__ bih_b, const float* __restrict__ bhh_b,
    int t)
{
    __shared__ ushort As[32 * 680];
    __shared__ float gs[4][512];
    int bid = blockIdx.x;
    int dir = bid >> 7, rem = bid & 127;
    int bt = rem >> 5, cb = rem & 31;
    int b0 = bt * 32;
    int tid = threadIdx.x;
    int tt = dir ? (255 - t) : t;
    const ushort* hin = hb_in + (size_t)dir * 65536;
    ushort* hout = hb_out + (size_t)dir * 65536;
    float* hf = hf32 + (size_t)dir * 65536;
    const float* bih = dir ? bih_b : bih_f;
    const float* bhh = dir ? bhh_b : bhh_f;
    const ushort* xr = xb16 + (size_t)tt * (B_ * 160);

    // stage A: 84 16B-chunks per row (20 x-part, 64 h-part), 32 rows
    for (int i = 0; i < 11; ++i) {
        int c = tid + i * 256;
        if (c < 2688) {
            int row = c / 84;
            int off = c - row * 84;
            const ushort* src = (off < 20)
                ? xr + (size_t)(b0 + row) * 160 + off * 8
                : hin + (size_t)(b0 + row) * 512 + (off - 20) * 8;
            uint4 v = *(const uint4*)src;
            *(uint4*)((char*)As + row * 1360 + off * 16) = v;
        }
    }
    __syncthreads();

    int lane = tid & 63, wv = tid >> 6;
    int m = lane & 15, kb = lane >> 4;
    int nk  = (wv == 2) ? 5 : (wv == 3) ? 16 : 21;
    int ksb = (wv == 0) ? 0 : (wv == 1) ? 21 : (wv == 2) ? 42 : 47;
    int kcol0 = (wv == 3) ? 160 : 0;
    const ushort* Bp = WE + ((size_t)((dir * 32 + cb) * 63 + ksb)) * 512 + lane * 8;
    int ai0 = m * 680 + kcol0 + kb * 8;
    int ai1 = (16 + m) * 680 + kcol0 + kb * 8;
    f32x4 acc0 = {0.f, 0.f, 0.f, 0.f}, acc1 = {0.f, 0.f, 0.f, 0.f};
    for (int ks = 0; ks < nk; ++ks) {
        bf16x8 bfr = *(const bf16x8*)(Bp + (size_t)ks * 512);
        bf16x8 a0 = *(const bf16x8*)&As[ai0 + ks * 32];
        bf16x8 a1 = *(const bf16x8*)&As[ai1 + ks * 32];
        acc0 = __builtin_amdgcn_mfma_f32_16x16x32_bf16(a0, bfr, acc0, 0, 0, 0);
        acc1 = __builtin_amdgcn_mfma_f32_16x16x32_bf16(a1, bfr, acc1, 0, 0, 0);
    }
    #pragma unroll
    for (int i = 0; i < 4; ++i) {
        gs[wv][(kb * 4 + i) * 16 + m] = acc0[i];
        gs[wv][(16 + kb * 4 + i) * 16 + m] = acc1[i];
    }
    __syncthreads();

    for (int o = tid; o < 512; o += 256) {
        int b = o >> 4, c = o & 15;
        int j = cb * 16 + c;
        float r = sigf(gs[0][o] + bih[j] + bhh[j]);
        float z = sigf(gs[1][o] + bih[512 + j] + bhh[512 + j]);
        float nn = tanhf(gs[2][o] + bih[1024 + j] + r * (gs[3][o] + bhh[1024 + j]));
        size_t gi = (size_t)(b0 + b) * 512 + j;
        float hp = hf[gi];
        float hv = (1.f - z) * nn + z * hp;
        hf[gi] = hv;
        hout[gi] = f2bf(hv);
    }
}

// Decoder step: grid 128 = bt(4) x cb(32); block 256 = 4 waves.
// planes: p0 r, p1 z, p2 gi_n (fused), p3 gh_n; all K=512.
// mode 1 (first step): gi terms read from gi0 (precomputed from note0); p2 idle.
__global__ __launch_bounds__(256) void dec_step(
    const ushort* __restrict__ hsrc, const ushort* __restrict__ WD,
    ushort* __restrict__ hdst, float* __restrict__ hf,
    const float* __restrict__ bfi, const float* __restrict__ bhh,
    const float* __restrict__ gi0, int mode)
{
    __shared__ ushort As[32 * 520];
    __shared__ float gs[4][512];
    int bid = blockIdx.x;
    int bt = bid >> 5, cb = bid & 31;
    int b0 = bt * 32;
    int tid = threadIdx.x;
    #pragma unroll
    for (int i = 0; i < 8; ++i) {
        int c = tid + i * 256;
        int row = c >> 6, off = c & 63;
        uint4 v = *(const uint4*)(hsrc + (size_t)(b0 + row) * 512 + off * 8);
        *(uint4*)((char*)As + row * 1040 + off * 16) = v;
    }
    __syncthreads();

    int lane = tid & 63, wv = tid >> 6;
    int m = lane & 15, kb = lane >> 4;
    int nk = (mode == 1 && wv == 2) ? 0 : 16;
    const ushort* Bp = WD + ((size_t)(cb * 64 + wv * 16)) * 512 + lane * 8;
    int ai0 = m * 520 + kb * 8;
    int ai1 = (16 + m) * 520 + kb * 8;
    f32x4 acc0 = {0.f, 0.f, 0.f, 0.f}, acc1 = {0.f, 0.f, 0.f, 0.f};
    for (int ks = 0; ks < nk; ++ks) {
        bf16x8 bfr = *(const bf16x8*)(Bp + (size_t)ks * 512);
        bf16x8 a0 = *(const bf16x8*)&As[ai0 + ks * 32];
        bf16x8 a1 = *(const bf16x8*)&As[ai1 + ks * 32];
        acc0 = __builtin_amdgcn_mfma_f32_16x16x32_bf16(a0, bfr, acc0, 0, 0, 0);
        acc1 = __builtin_amdgcn_mfma_f32_16x16x32_bf16(a1, bfr, acc1, 0, 0, 0);
    }
    #pragma unroll
    for (int i = 0; i < 4; ++i) {
        gs[wv][(kb * 4 + i) * 16 + m] = acc0[i];
        gs[wv][(16 + kb * 4 + i) * 16 + m] = acc1[i];
    }
    __syncthreads();

    for (int o = tid; o < 512; o += 256) {
        int b = o >> 4, c = o & 15;
        int j = cb * 16 + c;
        float ir, iz, inn;
        if (mode == 1) {
            const float* g = gi0 + (size_t)(b0 + b) * G3_;
            ir = g[j]; iz = g[512 + j]; inn = g[1024 + j];
        } else {
            ir = bfi[j]; iz = bfi[512 + j]; inn = bfi[1024 + j];
        }
        float r = sigf(gs[0][o] + ir + bhh[j]);
        float z = sigf(gs[1][o] + iz + bhh[512 + j]);
        float nn = tanhf(gs[2][o] + inn + r * (gs[3][o] + bhh[1024 + j]));
        size_t gi = (size_t)(b0 + b) * 512 + j;
        float hp = hf[gi];
        float hv = (1.f - z) * nn + z * hp;
        hf[gi] = hv;
        hdst[gi] = f2bf(hv);
    }
}

// all notes at end: hist [255][128][512] bf16 @ Wdec1.T + b -> out[:,t,:]
__global__ __launch_bounds__(256) void notes_all(
    const ushort* __restrict__ hist, const ushort4* __restrict__ Wd,
    const float* __restrict__ bd, float* __restrict__ out)
{
    int mb = blockIdx.x;   // 0..2039 (16 hist rows each)
    int nb = blockIdx.y;   // 0..7
    __shared__ ushort hs[16 * 512];
    int tid = threadIdx.x;
    int m0 = mb * 16;
    #pragma unroll
    for (int i = 0; i < 4; ++i) {
        int c = tid + i * 256;
        int row = c >> 6, off = c & 63;
        *(uint4*)&hs[row * 512 + off * 8] =
            *(const uint4*)&hist[(size_t)(m0 + row) * 512 + off * 8];
    }
    __syncthreads();
    int n = nb * 16 + (tid & 15), r = tid >> 4;
    int mrow = m0 + r;
    int ti = mrow >> 7, b = mrow & 127;
    float acc = 0.f;
    #pragma unroll 4
    for (int kc = 0; kc < 128; ++kc) {
        ushort4 u = Wd[(size_t)kc * 128 + n];
        ushort4 h4 = *(const ushort4*)&hs[r * 512 + kc * 4];
        acc += bf2f(h4.x) * bf2f(u.x) + bf2f(h4.y) * bf2f(u.y)
             + bf2f(h4.z) * bf2f(u.z) + bf2f(h4.w) * bf2f(u.w);
    }
    out[((size_t)b * T_ + (ti + 1)) * IN_ + n] = acc + bd[n];
}

// =============== MLP GEMM (fp32 A, bf16 tiled W) ===============
__global__ __launch_bounds__(256) void gemm_t4(
    const float* __restrict__ A, const ushort4* __restrict__ Wt,
    const float* __restrict__ bias, float* __restrict__ C,
    int M, int N, int K, int act)
{
    int nb = blockIdx.x, mb = blockIdx.y;
    int tid = threadIdx.x;
    int n = nb * 64 + (tid & 63);
    int mq = tid >> 6;
    int m0 = mb * 32;
    __shared__ float Asm[32][36];
    float acc[8];
    #pragma unroll
    for (int i = 0; i < 8; ++i) acc[i] = 0.f;
    for (int k0 = 0; k0 < K; k0 += 32) {
        int r = tid >> 3, c = (tid & 7) << 2;
        float4 v = *(const float4*)&A[(size_t)(m0 + r) * K + k0 + c];
        Asm[r][c] = v.x; Asm[r][c+1] = v.y; Asm[r][c+2] = v.z; Asm[r][c+3] = v.w;
        __syncthreads();
        #pragma unroll
        for (int kc = 0; kc < 8; ++kc) {
            float w0 = 0.f, w1 = 0.f, w2 = 0.f, w3 = 0.f;
            if (n < N) {
                ushort4 u = Wt[(size_t)((k0 >> 2) + kc) * N + n];
                w0 = bf2f(u.x); w1 = bf2f(u.y); w2 = bf2f(u.z); w3 = bf2f(u.w);
            }
            #pragma unroll
            for (int i = 0; i < 8; ++i) {
                int m = mq * 8 + i;
                acc[i] += Asm[m][kc*4+0]*w0 + Asm[m][kc*4+1]*w1
                        + Asm[m][kc*4+2]*w2 + Asm[m][kc*4+3]*w3;
            }
        }
        __syncthreads();
    }
    if (n < N) {
        #pragma unroll
        for (int i = 0; i < 8; ++i) {
            int m = m0 + mq * 8 + i;
            float v = acc[i] + bias[n];
            if (act == 1) v = (v >= 0.f) ? v : 0.01f * v;
            C[(size_t)m * N + n] = v;
        }
    }
}

__global__ void z_k(const float* __restrict__ out, const float* __restrict__ eps,
                    const float* __restrict__ genre, float* __restrict__ zc) {
    int id = blockIdx.x * 256 + threadIdx.x;
    if (id >= B_ * L_) return;
    int b = id >> 8, c = id & 255;
    float v;
    if (c < LG_) {
        float mu = out[MU_OFF + (size_t)b * LG_ + c];
        float lv = out[LV_OFF + (size_t)b * LG_ + c];
        v = mu + expf(0.5f * lv) * eps[(size_t)b * LG_ + c];
    } else {
        v = genre[(size_t)b * G_ + (c - LG_)];
    }
    zc[id] = v;
}

// =============== host ===============
extern "C" void kernel_launch(void* const* d_in, const int* in_sizes, int n_in,
                              void* d_out, int out_size, void* d_ws, size_t ws_size,
                              hipStream_t stream) {
    (void)in_sizes; (void)n_in; (void)out_size; (void)ws_size;
    const float* x      = (const float*)d_in[0];
    const float* genre  = (const float*)d_in[1];
    const float* eps    = (const float*)d_in[2];
    const float* Wih_e  = (const float*)d_in[3];
    const float* Whh_e  = (const float*)d_in[4];
    const float* bih_e  = (const float*)d_in[5];
    const float* bhh_e  = (const float*)d_in[6];
    const float* Wih_be = (const float*)d_in[7];
    const float* Whh_be = (const float*)d_in[8];
    const float* bih_be = (const float*)d_in[9];
    const float* bhh_be = (const float*)d_in[10];
    const float* Wih_d  = (const float*)d_in[11];
    const float* Whh_d  = (const float*)d_in[12];
    const float* bih_d  = (const float*)d_in[13];
    const float* bhh_d  = (const float*)d_in[14];
    const float* W_mu0  = (const float*)d_in[15];
    const float* b_mu0  = (const float*)d_in[16];
    const float* W_mu1  = (const float*)d_in[17];
    const float* b_mu1  = (const float*)d_in[18];
    const float* W_lv0  = (const float*)d_in[19];
    const float* b_lv0  = (const float*)d_in[20];
    const float* W_lv1  = (const float*)d_in[21];
    const float* b_lv1  = (const float*)d_in[22];
    const float* W_lat0 = (const float*)d_in[23];
    const float* b_lat0 = (const float*)d_in[24];
    const float* W_lat1 = (const float*)d_in[25];
    const float* b_lat1 = (const float*)d_in[26];
    const float* W_dec1 = (const float*)d_in[27];
    const float* b_dec1 = (const float*)d_in[28];
    float* out = (float*)d_out;

    char* ws = (char*)d_ws;
    size_t off = 0;
    auto alloc = [&](size_t bytes) -> char* {
        char* p = ws + off;
        off = (off + bytes + 255) & ~(size_t)255;
        return p;
    };
    ushort* xb16  = (ushort*)alloc((size_t)T_ * B_ * 160 * 2);        // 10.5 MB
    ushort* WE    = (ushort*)alloc((size_t)2 * 32 * 63 * 512 * 2);    // 4.1 MB
    ushort* WD2   = (ushort*)alloc((size_t)32 * 64 * 512 * 2);        // 2.1 MB
    ushort* WD1   = (ushort*)alloc((size_t)32 * 64 * 512 * 2);        // 2.1 MB
    float*  Wf    = (float*)alloc((size_t)G3_ * H_ * 4);              // 3.1 MB
    float*  bfi   = (float*)alloc(G3_ * 4);
    ushort* hb_e  = (ushort*)alloc((size_t)4 * 65536 * 2);            // [pp][dir][128][512]
    float*  hf_e  = (float*)alloc((size_t)2 * 65536 * 4);             // [dir][128][512]
    ushort* hist  = (ushort*)alloc((size_t)255 * 65536 * 2);          // 33.4 MB
    ushort* hdec0 = (ushort*)alloc((size_t)65536 * 2);
    float*  note0f= (float*)alloc((size_t)B_ * 128 * 4);
    float*  gi0   = (float*)alloc((size_t)B_ * G3_ * 4);
    float*  hidden= (float*)alloc((size_t)B_ * E_ * 4);
    float*  t0buf = (float*)alloc((size_t)B_ * E_ * 4);
    float*  t1buf = (float*)alloc((size_t)B_ * E_ * 4);
    float*  zcbuf = (float*)alloc((size_t)B_ * L_ * 4);
    float*  t2buf = (float*)alloc((size_t)B_ * L_ * 4);
    float*  t3buf = (float*)alloc((size_t)B_ * H_ * 4);               // decoder fp32 carry

    ushort4* T_Wmu0  = (ushort4*)alloc((size_t)256 * E_ * 8);
    ushort4* T_Wmu1  = (ushort4*)alloc((size_t)256 * LG_ * 8);
    ushort4* T_Wlv0  = (ushort4*)alloc((size_t)256 * E_ * 8);
    ushort4* T_Wlv1  = (ushort4*)alloc((size_t)256 * LG_ * 8);
    ushort4* T_Wlat0 = (ushort4*)alloc((size_t)64 * L_ * 8);
    ushort4* T_Wlat1 = (ushort4*)alloc((size_t)64 * H_ * 8);
    ushort4* T_Wdec1 = (ushort4*)alloc((size_t)128 * IN_ * 8);
    ushort4* T_Wihd  = (ushort4*)alloc((size_t)32 * G3_ * 8);

    // ---- prep ----
    xpad_k<<<(T_ * B_ * 160 + 255) / 256, 256, 0, stream>>>(x, xb16);
    pack_we<<<1008, 256, 0, stream>>>(Wih_e, Whh_e, Wih_be, Whh_be, WE);
    wfused_k<<<(G3_ * H_ + 255) / 256, 256, 0, stream>>>(Wih_d, W_dec1, Wf);
    bfi_k<<<6, 256, 0, stream>>>(Wih_d, b_dec1, bih_d, bfi);
    pack_wd<<<512, 256, 0, stream>>>(Wf, Whh_d, WD2, 1);
    pack_wd<<<512, 256, 0, stream>>>(Wf, Whh_d, WD1, 0);
    zero_init<<<1024, 256, 0, stream>>>(hb_e, hf_e);
    note0_k2<<<(B_ * IN_ + 255) / 256, 256, 0, stream>>>(x, out, note0f);

    auto tile = [&](const float* W, ushort4* dst, int N, int K) {
        int KC = (K + 3) / 4;
        tile_w<<<(KC * N + 255) / 256, 256, 0, stream>>>(W, dst, N, K, KC);
    };
    tile(W_mu0,  T_Wmu0,  E_,  E_);
    tile(W_mu1,  T_Wmu1,  LG_, E_);
    tile(W_lv0,  T_Wlv0,  E_,  E_);
    tile(W_lv1,  T_Wlv1,  LG_, E_);
    tile(W_lat0, T_Wlat0, L_,  L_);
    tile(W_lat1, T_Wlat1, H_,  L_);
    tile(W_dec1, T_Wdec1, IN_, H_);
    tile(Wih_d,  T_Wihd,  G3_, IN_);

    // ---- encoders: 256 steps, both directions per launch ----
    for (int t = 0; t < T_; ++t) {
        int pp = t & 1;
        enc_step<<<256, 256, 0, stream>>>(
            xb16, WE,
            hb_e + (size_t)pp * 131072, hb_e + (size_t)(pp ^ 1) * 131072,
            hf_e, bih_e, bhh_e, bih_be, bhh_be, t);
    }

    // ---- MLP bottleneck ----
    concat_h<<<(B_ * E_ + 255) / 256, 256, 0, stream>>>(hf_e, hidden);
    {
        dim3 g1(16, 4), g2(4, 4), g3(4, 4), g4(8, 4), g5(24, 4);
        gemm_t4<<<g1, 256, 0, stream>>>(hidden, T_Wmu0, b_mu0, t0buf, B_, E_, E_, 1);
        gemm_t4<<<g2, 256, 0, stream>>>(t0buf, T_Wmu1, b_mu1, out + MU_OFF, B_, LG_, E_, 0);
        gemm_t4<<<g1, 256, 0, stream>>>(hidden, T_Wlv0, b_lv0, t1buf, B_, E_, E_, 1);
        gemm_t4<<<g2, 256, 0, stream>>>(t1buf, T_Wlv1, b_lv1, out + LV_OFF, B_, LG_, E_, 0);
        z_k<<<(B_ * L_ + 255) / 256, 256, 0, stream>>>(out, eps, genre, zcbuf);
        gemm_t4<<<g3, 256, 0, stream>>>(zcbuf, T_Wlat0, b_lat0, t2buf, B_, L_, L_, 1);
        gemm_t4<<<g4, 256, 0, stream>>>(t2buf, T_Wlat1, b_lat1, t3buf, B_, H_, L_, 0);
        // gi0 = note0 @ Wih_d.T + bih_d   (for decoder step 1)
        gemm_t4<<<g5, 256, 0, stream>>>(note0f, T_Wihd, bih_d, gi0, B_, G3_, IN_, 0);
    }
    cvt_h0<<<(B_ * H_ + 255) / 256, 256, 0, stream>>>(t3buf, hdec0);

    // ---- decoder: 255 steps (h-only recurrence via Wfused) ----
    for (int t = 1; t < T_; ++t) {
        const ushort* src = (t == 1) ? hdec0 : hist + (size_t)(t - 2) * 65536;
        ushort* dst = hist + (size_t)(t - 1) * 65536;
        const ushort* W = (t == 1) ? WD1 : WD2;
        dec_step<<<128, 256, 0, stream>>>(src, W, dst, t3buf, bfi, bhh_d, gi0,
                                          (t == 1) ? 1 : 2);
    }

    // ---- all notes ----
    {
        dim3 g(2040, 8);
        notes_all<<<g, 256, 0, stream>>>(hist, T_Wdec1, b_dec1, out);
    }
}